// Round 15
// baseline (152.951 us; speedup 1.0000x reference)
//
#include <hip/hip_runtime.h>
#include <hip/hip_bf16.h>
#include <cstdint>
#include <cstddef>

typedef __attribute__((ext_vector_type(8))) short short8;
typedef __attribute__((ext_vector_type(4))) float f32x4;
typedef __attribute__((ext_vector_type(16))) float f32x16;
typedef __attribute__((ext_vector_type(4))) unsigned int u32x4;
typedef unsigned short u16;
typedef unsigned int u32;

#define B_ 2
#define C_ 2048
#define D_ 1024
#define H_ 16
#define HD_ 64
#define LOG2E 1.4426950408889634f

static __device__ __forceinline__ u16 f2b(float f) {
  u32 x = __builtin_bit_cast(u32, f);
  x += 0x7FFFu + ((x >> 16) & 1u);
  return (u16)(x >> 16);
}
static __device__ __forceinline__ float b2f(u16 v) {
  return __builtin_bit_cast(float, (u32)v << 16);
}

// segment table for 256-row q-tiles (qt 0..7, ntiles = 4qt+4, seg cap 8):
// 20 segments/bh, sorted len desc (16x len-8, then 4x len-4).
// enc = qt | (seg<<4) | ((nseg-1)<<6).
__device__ const unsigned char SEGTAB[20] = {
  1, 66, 67, 83, 132, 148, 133, 149, 165, 198, 214, 230, 199, 215, 231, 247,
  0, 82, 164, 246};

// ---------------- fused preprocessing ----------------
// grid 5120 x 256thr:
//   [0,2048)   : convert hs f32 -> bf16 (4M elems)
//   [2048,2816): transpose-convert Wqkv [1024][3072] -> [3072][1024] bf16
//   [2816,3072): transpose-convert Wo   [1024][1024] -> [1024][1024] bf16
//   [3072,5120): per-(64q x 64k)-tile mask nonzero flags
static __device__ void tconv_body(const float* __restrict__ in, u16* __restrict__ out,
                                  int R, int Cc, int bx, int by, int t,
                                  float (*tile)[65]) {
  const int tC = bx * 64, tR = by * 64;
  const int r0 = t >> 4;
  const int c0 = (t & 15) * 4;
#pragma unroll
  for (int ii = 0; ii < 4; ++ii) {
    int r = ii * 16 + r0;
    float4 v = *reinterpret_cast<const float4*>(&in[(size_t)(tR + r) * Cc + tC + c0]);
    tile[r][c0] = v.x; tile[r][c0 + 1] = v.y; tile[r][c0 + 2] = v.z; tile[r][c0 + 3] = v.w;
  }
  __syncthreads();
#pragma unroll
  for (int ii = 0; ii < 4; ++ii) {
    int c = ii * 16 + r0;
    ushort4 o;
    o.x = f2b(tile[c0 + 0][c]);
    o.y = f2b(tile[c0 + 1][c]);
    o.z = f2b(tile[c0 + 2][c]);
    o.w = f2b(tile[c0 + 3][c]);
    *reinterpret_cast<ushort4*>(&out[(size_t)(tC + c) * R + tR + c0]) = o;
  }
}

__global__ __launch_bounds__(256) void k_prep(
    const float* __restrict__ hs, u16* __restrict__ hsb,
    const float* __restrict__ Wqkv, u16* __restrict__ Wqkvt,
    const float* __restrict__ Wo, u16* __restrict__ Wot,
    const float* __restrict__ mask, u32* __restrict__ flags)
{
  __shared__ float tile[64][65];
  __shared__ int sh[4];
  const int bid = blockIdx.x;
  const int t = threadIdx.x;
  if (bid < 2048) {
    // convert
    int i = (bid * 256 + t) * 4;
    const int n = 4096 * 1024;
    const int stride = 2048 * 256 * 4;
    for (; i < n; i += stride) {
      float4 v = *reinterpret_cast<const float4*>(hs + i);
      ushort4 o;
      o.x = f2b(v.x); o.y = f2b(v.y); o.z = f2b(v.z); o.w = f2b(v.w);
      *reinterpret_cast<ushort4*>(hsb + i) = o;
    }
  } else if (bid < 2816) {
    const int r = bid - 2048;
    tconv_body(Wqkv, Wqkvt, 1024, 3072, r % 48, r / 48, t, tile);
  } else if (bid < 3072) {
    const int r = bid - 2816;
    tconv_body(Wo, Wot, 1024, 1024, r % 16, r / 16, t, tile);
  } else {
    const int mb = bid - 3072;
    const int kt = mb & 31, qs = (mb >> 5) & 31, b = mb >> 10;
    const float* base = mask + ((size_t)b * C_ + qs * 64) * C_ + kt * 64;
    const int row = t >> 2, c0 = (t & 3) * 16;
    int any = 0;
#pragma unroll
    for (int i = 0; i < 4; ++i) {
      float4 v = *reinterpret_cast<const float4*>(base + (size_t)row * C_ + c0 + i * 4);
      any |= (v.x != 0.f) | (v.y != 0.f) | (v.z != 0.f) | (v.w != 0.f);
    }
    const unsigned long long bal = __ballot(any);
    if ((t & 63) == 0) sh[t >> 6] = (bal != 0ull);
    __syncthreads();
    if (t == 0) flags[mb] = (u32)(sh[0] | sh[1] | sh[2] | sh[3]);
  }
}

// ---------------- async global->LDS, 16B per lane ----------------
#define GLL16(gptr, lptr) __builtin_amdgcn_global_load_lds( \
    (const __attribute__((address_space(1))) u32*)(gptr),   \
    (__attribute__((address_space(3))) u32*)(lptr), 16, 0, 0)

// ---------------- BMx128 bf16 GEMM (BK=64, swizzled LDS), C = A * Bt^T + bias ----
// EPI 0: scatter Q/K -> [B,H,C,hd], V -> transposed [B,H,hd,C].  EPI 1: f32 C + bias.
template<int EPI, int BM>
__global__ __launch_bounds__(256) void k_gemm(
    const u16* __restrict__ A, const u16* __restrict__ Bt,
    int M, int N, int K, const float* __restrict__ bias,
    u16* __restrict__ Cq, u16* __restrict__ Ck, u16* __restrict__ Cv,
    float* __restrict__ Cf)
{
  constexpr int WCW = (BM == 128) ? 64 : 32;   // per-wave col width
  constexpr int NF = WCW / 16;                 // n-frags per wave
  __shared__ __align__(16) u16 As[BM * 64];
  __shared__ __align__(16) u16 Bs[128 * 64];
  const int t = threadIdx.x;
  const int l = t & 63, w = t >> 6;
  const int wr = (BM == 128) ? (w >> 1) : 0;
  const int wc = (BM == 128) ? (w & 1) : w;
  const int lr = l & 15, lg = l >> 4;
  const int swk = lr & 7;
  const int m0 = blockIdx.y * BM, n0 = blockIdx.x * 128;
  f32x4 acc[4][NF] = {};

  for (int k0 = 0; k0 < K; k0 += 64) {
#pragma unroll
    for (int s = 0; s < BM / 32; ++s) {        // A: BM*8 16B-units
      const int u = s * 256 + t;
      const int row = u >> 3, slot = (u & 7) ^ (row & 7);
      GLL16(A + (size_t)(m0 + row) * K + k0 + (slot << 3), As + (u << 3));
    }
#pragma unroll
    for (int s = 0; s < 4; ++s) {              // B: 1024 16B-units
      const int u = s * 256 + t;
      const int row = u >> 3, slot = (u & 7) ^ (row & 7);
      GLL16(Bt + (size_t)(n0 + row) * K + k0 + (slot << 3), Bs + (u << 3));
    }
    __syncthreads();
    short8 af[2][4], bfr[2][NF];
#pragma unroll
    for (int s = 0; s < 2; ++s) {
#pragma unroll
      for (int m = 0; m < 4; ++m)
        af[s][m] = *reinterpret_cast<const short8*>(
            &As[((wr * 64 + m * 16 + lr) << 6) + (((s * 4 + lg) ^ swk) << 3)]);
#pragma unroll
      for (int n = 0; n < NF; ++n)
        bfr[s][n] = *reinterpret_cast<const short8*>(
            &Bs[((wc * WCW + n * 16 + lr) << 6) + (((s * 4 + lg) ^ swk) << 3)]);
    }
#pragma unroll
    for (int s = 0; s < 2; ++s)
#pragma unroll
      for (int m = 0; m < 4; ++m)
#pragma unroll
        for (int n = 0; n < NF; ++n)
          acc[m][n] = __builtin_amdgcn_mfma_f32_16x16x32_bf16(af[s][m], bfr[s][n], acc[m][n], 0, 0, 0);
    __syncthreads();
  }

#pragma unroll
  for (int m = 0; m < 4; ++m) {
    const int mg = m0 + wr * 64 + m * 16 + lg * 4;
    const int bq = mg >> 11, c0 = mg & 2047;
#pragma unroll
    for (int n = 0; n < NF; ++n) {
      const int ng = n0 + wc * WCW + n * 16 + lr;
      const float bia = bias[ng];
      if (EPI == 0) {
        const int reg = ng >> 10, d = ng & 1023, h = d >> 6, e = d & 63;
        if (reg == 2) {
          u16* vp = Cv + (((size_t)(bq * H_ + h) * HD_ + e) << 11) + c0;  // [B,H,hd,C]
#pragma unroll
          for (int j = 0; j < 4; ++j) vp[j] = f2b(acc[m][n][j] + bia);
        } else {
          u16* dst = (reg == 0) ? Cq : Ck;
#pragma unroll
          for (int j = 0; j < 4; ++j)
            dst[(((size_t)(bq * H_ + h) * C_ + c0 + j) << 6) + e] = f2b(acc[m][n][j] + bia);
        }
      } else {
#pragma unroll
        for (int j = 0; j < 4; ++j)
          Cf[(size_t)(mg + j) * N + ng] = acc[m][n][j] + bia;
      }
    }
  }
}

// ---------------- causal flash attention (v14: barrier-free, K/V direct from L2) ----
// grid: 640 = 20 segs (SEGTAB) x 32 bh; 512 thr = 8 INDEPENDENT warps (no barriers,
// no LDS staging). Warp w owns q-rows qt*256+w*32..+31 with an EXACT causal loop
// bound. K/V fragments read directly from global (L2-resident: 512KB/bh).
// nseg==1: direct normalized output. nseg>1: normalized partial Ohat=O/l (bf16)
// + (m[log2 units], l) f32; k_merge combines (verified scheme).
// Body math identical to v9-v13 (verified) + T13 defer-max (exact wrt stored (m,l)).
__global__ __launch_bounds__(512) void k_attn(
    const u16* __restrict__ Q, const u16* __restrict__ Kb, const u16* __restrict__ Vt,
    const float* __restrict__ mask, const u32* __restrict__ flags,
    u16* __restrict__ O, u16* __restrict__ Opart, float2* __restrict__ ml)
{
  __shared__ __align__(16) u16 sep[8][2304];  // 36.9 KB, epilogue transpose only
  const int bid = blockIdx.x;
  const int bh = bid & 31;                    // bid%8 == bh%8 -> XCD-local K/V
  const int e = SEGTAB[bid >> 5];
  const int qt = e & 15, seg = (e >> 4) & 3, nseg = (e >> 6) + 1;
  const int ntiles = 4 * qt + 4;
  const int kt0 = seg * 8;
  const int kt1 = (kt0 + 8 < ntiles) ? kt0 + 8 : ntiles;
  const int slotbase = (qt < 4) ? (qt - 2) * 2
                     : (qt < 6) ? 4 + (qt - 4) * 3
                     : 10 + (qt - 6) * 4;
  const int slot = bh * 18 + slotbase + seg;  // valid when nseg>1

  const int b = bh >> 4, h = bh & 15;
  const int t = threadIdx.x;
  const int l = t & 63, w = t >> 6;           // 8 warps
  const int q = l & 31, hi = l >> 5;

  const u16* Kbh = Kb + (size_t)bh * (C_ * HD_);
  const u16* Vbh = Vt + (size_t)bh * (HD_ * C_);

  const int q0w = qt * 256 + w * 32;
  const int qg = q0w + q;
  const int qmaxw = q0w + 31;
  const int ktw1 = min(kt1, (qmaxw >> 6) + 1);   // exact per-warp causal bound

  // Q frags (B-operand: lane q=lane&31, k-slice=8*hi+i), pre-scaled by hd^-0.5 * log2e
  short8 aq[4];
  {
    const u16* qp = Q + ((size_t)bh * C_ + qg) * HD_ + hi * 8;
#pragma unroll
    for (int kh = 0; kh < 4; ++kh) {
      short8 v = *reinterpret_cast<const short8*>(qp + kh * 16);
#pragma unroll
      for (int i = 0; i < 8; ++i) {
        const float f = b2f((u16)v[i]) * (0.125f * LOG2E);
        v[i] = (short)f2b(f);
      }
      aq[kh] = v;
    }
  }

  // preload mask-tile flags for this segment as a bitmask (no in-loop load)
  u32 fbits = 0;
  {
    const u32* fp = flags + (size_t)(b * 32 + (q0w >> 6)) * 32 + kt0;
#pragma unroll
    for (int i = 0; i < 8; ++i) fbits |= (fp[i] ? 1u : 0u) << i;
  }

  f32x16 oa0 = {}, oa1 = {};
  float mrun = -INFINITY, srun = 0.f;
  const float* mrow = mask + ((size_t)b * C_ + qg) * C_;

  // per-warp K/V base addresses (direct global reads, 16B aligned)
  const u16* kb0 = Kbh + (((size_t)q) << 6) + hi * 8;          // + kt*64*64 ; +32*64
  const u16* vb0 = Vbh + (((size_t)q) << 11) + hi * 8;         // + kt*64 ; +32*2048

#pragma unroll 1
  for (int kt = kt0; kt < ktw1; ++kt) {
    // K fragments direct from L2
    const u16* kp0 = kb0 + ((size_t)kt << 12);
    const u16* kp1 = kp0 + (32 << 6);
    short8 k0r[4], k1r[4];
#pragma unroll
    for (int kh = 0; kh < 4; ++kh) {
      k0r[kh] = *reinterpret_cast<const short8*>(kp0 + kh * 16);
      k1r[kh] = *reinterpret_cast<const short8*>(kp1 + kh * 16);
    }
    // S^T = K Q^T : D[key][q] (log2 units)
    f32x16 p0 = {}, p1 = {};
#pragma unroll
    for (int kh = 0; kh < 4; ++kh) {
      p0 = __builtin_amdgcn_mfma_f32_32x32x16_bf16(k0r[kh], aq[kh], p0, 0, 0, 0);
      p1 = __builtin_amdgcn_mfma_f32_32x32x16_bf16(k1r[kh], aq[kh], p1, 0, 0, 0);
    }
    // V fragments direct from L2 (issued early, consumed after softmax)
    const u16* vp0 = vb0 + kt * 64;
    const u16* vp1 = vp0 + (32 << 11);
    short8 v0r[4], v1r[4];
#pragma unroll
    for (int ks = 0; ks < 4; ++ks) {
      v0r[ks] = *reinterpret_cast<const short8*>(vp0 + ks * 16);
      v1r[ks] = *reinterpret_cast<const short8*>(vp1 + ks * 16);
    }

    // additive mask, scaled into log2 domain (only when tile nonzero)
    if ((fbits >> (kt - kt0)) & 1u) {
      const float* mp = mrow + kt * 64 + 4 * hi;
#pragma unroll
      for (int g = 0; g < 4; ++g) {
        const float4 m0 = *reinterpret_cast<const float4*>(mp + 8 * g);
        const float4 m1 = *reinterpret_cast<const float4*>(mp + 32 + 8 * g);
        p0[4*g+0] = fmaf(m0.x, LOG2E, p0[4*g+0]);
        p0[4*g+1] = fmaf(m0.y, LOG2E, p0[4*g+1]);
        p0[4*g+2] = fmaf(m0.z, LOG2E, p0[4*g+2]);
        p0[4*g+3] = fmaf(m0.w, LOG2E, p0[4*g+3]);
        p1[4*g+0] = fmaf(m1.x, LOG2E, p1[4*g+0]);
        p1[4*g+1] = fmaf(m1.y, LOG2E, p1[4*g+1]);
        p1[4*g+2] = fmaf(m1.z, LOG2E, p1[4*g+2]);
        p1[4*g+3] = fmaf(m1.w, LOG2E, p1[4*g+3]);
      }
    }
    // causal clamp (diagonal region only)
    if (kt * 64 + 63 > q0w) {
#pragma unroll
      for (int r = 0; r < 16; ++r) {
        const int kl = kt * 64 + (r & 3) + 8 * (r >> 2) + 4 * hi;
        if (kl > qg) p0[r] = -INFINITY;
        if (kl + 32 > qg) p1[r] = -INFINITY;
      }
    }

    // online softmax (exp2 domain) with T13 defer-max (THR=8 log2 units).
    float pm = -INFINITY;
#pragma unroll
    for (int r = 0; r < 16; ++r) pm = fmaxf(pm, fmaxf(p0[r], p1[r]));
    pm = fmaxf(pm, __shfl_xor(pm, 32));
    if (__ballot(pm > mrun + 8.f) != 0ull) {   // rescale only on >2^8 growth
      const float mn = fmaxf(fmaxf(mrun, pm), -1e30f);
      const float rs = exp2f(mrun - mn);       // first iter: exp2(-inf)=0
      srun *= rs;
      oa0 *= rs; oa1 *= rs;
      mrun = mn;
    }
    float sum = 0.f;
#pragma unroll
    for (int r = 0; r < 16; ++r) {
      p0[r] = exp2f(p0[r] - mrun); sum += p0[r];
      p1[r] = exp2f(p1[r] - mrun); sum += p1[r];
    }
    sum += __shfl_xor(sum, 32);
    srun += sum;

    // O^T += Vt x P : D[d][q].  PV B-frags in-register via cvt_pk + permlane32_swap.
    __builtin_amdgcn_s_setprio(1);
#pragma unroll
    for (int ks = 0; ks < 4; ++ks) {
      const int o = (ks & 1) * 8;
      u32 X, X2, Y, Y2;
      if (ks < 2) {
        asm("v_cvt_pk_bf16_f32 %0, %1, %2" : "=v"(X)  : "v"(p0[o+0]), "v"(p0[o+1]));
        asm("v_cvt_pk_bf16_f32 %0, %1, %2" : "=v"(X2) : "v"(p0[o+2]), "v"(p0[o+3]));
        asm("v_cvt_pk_bf16_f32 %0, %1, %2" : "=v"(Y)  : "v"(p0[o+4]), "v"(p0[o+5]));
        asm("v_cvt_pk_bf16_f32 %0, %1, %2" : "=v"(Y2) : "v"(p0[o+6]), "v"(p0[o+7]));
      } else {
        asm("v_cvt_pk_bf16_f32 %0, %1, %2" : "=v"(X)  : "v"(p1[o+0]), "v"(p1[o+1]));
        asm("v_cvt_pk_bf16_f32 %0, %1, %2" : "=v"(X2) : "v"(p1[o+2]), "v"(p1[o+3]));
        asm("v_cvt_pk_bf16_f32 %0, %1, %2" : "=v"(Y)  : "v"(p1[o+4]), "v"(p1[o+5]));
        asm("v_cvt_pk_bf16_f32 %0, %1, %2" : "=v"(Y2) : "v"(p1[o+6]), "v"(p1[o+7]));
      }
      asm("v_permlane32_swap_b32 %0, %1" : "+v"(X), "+v"(Y));
      asm("v_permlane32_swap_b32 %0, %1" : "+v"(X2), "+v"(Y2));
      const u32x4 bw = {X, X2, Y, Y2};
      const short8 bp = __builtin_bit_cast(short8, bw);
      oa0 = __builtin_amdgcn_mfma_f32_32x32x16_bf16(v0r[ks], bp, oa0, 0, 0, 0);
      oa1 = __builtin_amdgcn_mfma_f32_32x32x16_bf16(v1r[ks], bp, oa1, 0, 0, 0);
    }
    __builtin_amdgcn_s_setprio(0);
  }

  // epilogue: normalize (both paths), transpose via per-warp LDS (no barrier
  // needed: sep is per-warp, untouched by the loop), vector store.
  const float rinv = 1.f / srun;
  char* Swb = reinterpret_cast<char*>(sep[w]);
#pragma unroll
  for (int g = 0; g < 4; ++g) {
    const int d0 = 8 * g + 4 * hi;
    const float a0 = oa0[4*g+0] * rinv, a1 = oa0[4*g+1] * rinv;
    const float a2 = oa0[4*g+2] * rinv, a3 = oa0[4*g+3] * rinv;
    const float b0 = oa1[4*g+0] * rinv, b1 = oa1[4*g+1] * rinv;
    const float b2 = oa1[4*g+2] * rinv, b3 = oa1[4*g+3] * rinv;
    u32 w0, w1, w2, w3;
    asm("v_cvt_pk_bf16_f32 %0, %1, %2" : "=v"(w0) : "v"(a0), "v"(a1));
    asm("v_cvt_pk_bf16_f32 %0, %1, %2" : "=v"(w1) : "v"(a2), "v"(a3));
    asm("v_cvt_pk_bf16_f32 %0, %1, %2" : "=v"(w2) : "v"(b0), "v"(b1));
    asm("v_cvt_pk_bf16_f32 %0, %1, %2" : "=v"(w3) : "v"(b2), "v"(b3));
    *reinterpret_cast<uint2*>(Swb + q * 144 + d0 * 2) = make_uint2(w0, w1);
    *reinterpret_cast<uint2*>(Swb + q * 144 + (d0 + 32) * 2) = make_uint2(w2, w3);
  }
  asm volatile("" ::: "memory");              // order same-wave LDS write -> read
  const int q2 = l >> 1, hf = l & 1;
  if (nseg == 1) {
    u16* orow = O + ((size_t)b * C_ + q0w + q2) * D_ + h * 64 + hf * 32;
#pragma unroll
    for (int i = 0; i < 4; ++i) {
      const short8 v = *reinterpret_cast<const short8*>(Swb + q2 * 144 + hf * 64 + i * 16);
      *reinterpret_cast<short8*>(orow + i * 8) = v;
    }
  } else {
    u16* prow = Opart + (((size_t)slot * 256 + w * 32 + q2) << 6) + hf * 32;
#pragma unroll
    for (int i = 0; i < 4; ++i) {
      const short8 v = *reinterpret_cast<const short8*>(Swb + q2 * 144 + hf * 64 + i * 16);
      *reinterpret_cast<short8*>(prow + i * 8) = v;
    }
    if (hi == 0) ml[(size_t)slot * 256 + w * 32 + q] = make_float2(mrun, srun);
  }
}

// ---------------- merge split-KV partials (nseg 2..4) ----------------
// grid 192 = 6 qt (2..7) x 32 bh; 512 thr: thread -> (q = t>>1 in 0..255, dhalf = t&1)
// Partials are NORMALIZED: O = sum_s a_s*Ohat_s / sum_s a_s, a_s = 2^(m_s-M) l_s
__global__ __launch_bounds__(512) void k_merge(
    const u16* __restrict__ Opart, const float2* __restrict__ ml, u16* __restrict__ O)
{
  const int bid = blockIdx.x;
  const int bh = bid & 31;
  const int qt = 2 + (bid >> 5);
  const int nseg = (qt < 4) ? 2 : (qt < 6) ? 3 : 4;
  const int slotbase = (qt < 4) ? (qt - 2) * 2
                     : (qt < 6) ? 4 + (qt - 4) * 3
                     : 10 + (qt - 6) * 4;
  const int slot0 = bh * 18 + slotbase;
  const int b = bh >> 4, h = bh & 15;
  const int t = threadIdx.x;
  const int q = t >> 1, dh = t & 1;

  float m[4], l_[4];
  float M = -INFINITY;
#pragma unroll 4
  for (int s = 0; s < nseg; ++s) {
    const float2 v = ml[(size_t)(slot0 + s) * 256 + q];
    m[s] = v.x; l_[s] = v.y;
    M = fmaxf(M, v.x);
  }
  float a[4], L = 0.f;
#pragma unroll 4
  for (int s = 0; s < nseg; ++s) { a[s] = exp2f(m[s] - M) * l_[s]; L += a[s]; }
  const float rL = 1.f / L;

  float acc[32] = {};
#pragma unroll 4
  for (int s = 0; s < nseg; ++s) {
    const u16* op = Opart + (((size_t)(slot0 + s) * 256 + q) << 6) + dh * 32;
    const float ws = a[s] * rL;
#pragma unroll
    for (int i = 0; i < 4; ++i) {
      const short8 v = *reinterpret_cast<const short8*>(op + i * 8);
#pragma unroll
      for (int j = 0; j < 8; ++j) acc[i * 8 + j] += ws * b2f((u16)v[j]);
    }
  }
  u16* orow = O + ((size_t)b * C_ + qt * 256 + q) * D_ + h * 64 + dh * 32;
#pragma unroll
  for (int i = 0; i < 4; ++i) {
    short8 v;
#pragma unroll
    for (int j = 0; j < 8; ++j) v[j] = (short)f2b(acc[i * 8 + j]);
    *reinterpret_cast<short8*>(orow + i * 8) = v;
  }
}

extern "C" void kernel_launch(void* const* d_in, const int* in_sizes, int n_in,
                              void* d_out, int out_size, void* d_ws, size_t ws_size,
                              hipStream_t stream) {
  const float* hs   = (const float*)d_in[0];
  const float* mask = (const float*)d_in[1];
  const float* Wqkv = (const float*)d_in[2];
  const float* bqkv = (const float*)d_in[3];
  const float* Wo   = (const float*)d_in[4];
  const float* bo   = (const float*)d_in[5];
  float* out = (float*)d_out;
  char* ws = (char*)d_ws;

  // time-phased layout (peak 56 MB):
  u16*    hsb   = (u16*)(ws);                   // 8 MB, dead after gemm0
  u16*    Opart = (u16*)(ws);                   // attn phase (overlays hsb/Wqkvt)
  u16*    Wqkvt = (u16*)(ws + (8  << 20));      // 6 MB, dead after gemm0
  float2* mlbuf = (float2*)(ws + (19 << 20));   // 1.2 MB [576 slots][256]
  u32*    flags = (u32*)(ws + (20 << 20) + (1 << 19)); // 8 KB @20.5MB
  u16*    Wot   = (u16*)(ws + (21 << 20));      // 2 MB
  u16*    Qb    = (u16*)(ws + (24 << 20));      // 8 MB [2,16,2048,64]
  u16*    Kb    = (u16*)(ws + (32 << 20));      // 8 MB [2,16,2048,64]
  u16*    Vtb   = (u16*)(ws + (40 << 20));      // 8 MB [2,16,64,2048]
  u16*    AOb   = (u16*)(ws + (48 << 20));      // 8 MB [4096][1024]

  k_prep<<<5120, 256, 0, stream>>>(hs, hsb, Wqkv, Wqkvt, Wo, Wot, mask, flags);
  k_gemm<0, 128><<<dim3(24, 32), 256, 0, stream>>>(hsb, Wqkvt, 4096, 3072, 1024, bqkv,
                                                   Qb, Kb, Vtb, nullptr);
  k_attn<<<640, 512, 0, stream>>>(Qb, Kb, Vtb, mask, flags, AOb, Opart, mlbuf);
  k_merge<<<192, 512, 0, stream>>>(Opart, mlbuf, AOb);
  k_gemm<1, 64><<<dim3(8, 64), 256, 0, stream>>>(AOb, Wot, 4096, 1024, 1024, bo,
                                                 nullptr, nullptr, nullptr, out);
}

// Round 16
// 124.141 us; speedup vs baseline: 1.2321x; 1.2321x over previous
//
#include <hip/hip_runtime.h>
#include <hip/hip_bf16.h>
#include <cstdint>
#include <cstddef>

typedef __attribute__((ext_vector_type(8))) short short8;
typedef __attribute__((ext_vector_type(4))) float f32x4;
typedef __attribute__((ext_vector_type(16))) float f32x16;
typedef unsigned short u16;
typedef unsigned int u32;

#define B_ 2
#define C_ 2048
#define D_ 1024
#define H_ 16
#define HD_ 64

static __device__ __forceinline__ u16 f2b(float f) {
  u32 x = __builtin_bit_cast(u32, f);
  x += 0x7FFFu + ((x >> 16) & 1u);
  return (u16)(x >> 16);
}
static __device__ __forceinline__ float b2f(u16 v) {
  return __builtin_bit_cast(float, (u32)v << 16);
}

// ---------------- fused preprocessing ----------------
// grid 5120 x 256thr:
//   [0,2048)   : convert hs f32 -> bf16 (4M elems)
//   [2048,2816): transpose-convert Wqkv [1024][3072] -> [3072][1024] bf16
//   [2816,3072): transpose-convert Wo   [1024][1024] -> [1024][1024] bf16
//   [3072,5120): per-(64q x 64k)-tile mask nonzero flags
static __device__ void tconv_body(const float* __restrict__ in, u16* __restrict__ out,
                                  int R, int Cc, int bx, int by, int t,
                                  float (*tile)[65]) {
  const int tC = bx * 64, tR = by * 64;
  const int r0 = t >> 4;
  const int c0 = (t & 15) * 4;
#pragma unroll
  for (int ii = 0; ii < 4; ++ii) {
    int r = ii * 16 + r0;
    float4 v = *reinterpret_cast<const float4*>(&in[(size_t)(tR + r) * Cc + tC + c0]);
    tile[r][c0] = v.x; tile[r][c0 + 1] = v.y; tile[r][c0 + 2] = v.z; tile[r][c0 + 3] = v.w;
  }
  __syncthreads();
#pragma unroll
  for (int ii = 0; ii < 4; ++ii) {
    int c = ii * 16 + r0;
    ushort4 o;
    o.x = f2b(tile[c0 + 0][c]);
    o.y = f2b(tile[c0 + 1][c]);
    o.z = f2b(tile[c0 + 2][c]);
    o.w = f2b(tile[c0 + 3][c]);
    *reinterpret_cast<ushort4*>(&out[(size_t)(tC + c) * R + tR + c0]) = o;
  }
}

__global__ __launch_bounds__(256) void k_prep(
    const float* __restrict__ hs, u16* __restrict__ hsb,
    const float* __restrict__ Wqkv, u16* __restrict__ Wqkvt,
    const float* __restrict__ Wo, u16* __restrict__ Wot,
    const float* __restrict__ mask, u32* __restrict__ flags)
{
  __shared__ float tile[64][65];
  __shared__ int sh[4];
  const int bid = blockIdx.x;
  const int t = threadIdx.x;
  if (bid < 2048) {
    int i = (bid * 256 + t) * 4;
    const int n = 4096 * 1024;
    const int stride = 2048 * 256 * 4;
    for (; i < n; i += stride) {
      float4 v = *reinterpret_cast<const float4*>(hs + i);
      ushort4 o;
      o.x = f2b(v.x); o.y = f2b(v.y); o.z = f2b(v.z); o.w = f2b(v.w);
      *reinterpret_cast<ushort4*>(hsb + i) = o;
    }
  } else if (bid < 2816) {
    const int r = bid - 2048;
    tconv_body(Wqkv, Wqkvt, 1024, 3072, r % 48, r / 48, t, tile);
  } else if (bid < 3072) {
    const int r = bid - 2816;
    tconv_body(Wo, Wot, 1024, 1024, r % 16, r / 16, t, tile);
  } else {
    const int mb = bid - 3072;
    const int kt = mb & 31, qs = (mb >> 5) & 31, b = mb >> 10;
    const float* base = mask + ((size_t)b * C_ + qs * 64) * C_ + kt * 64;
    const int row = t >> 2, c0 = (t & 3) * 16;
    int any = 0;
#pragma unroll
    for (int i = 0; i < 4; ++i) {
      float4 v = *reinterpret_cast<const float4*>(base + (size_t)row * C_ + c0 + i * 4);
      any |= (v.x != 0.f) | (v.y != 0.f) | (v.z != 0.f) | (v.w != 0.f);
    }
    const unsigned long long bal = __ballot(any);
    if ((t & 63) == 0) sh[t >> 6] = (bal != 0ull);
    __syncthreads();
    if (t == 0) flags[mb] = (u32)(sh[0] | sh[1] | sh[2] | sh[3]);
  }
}

// ---------------- async global->LDS, 16B per lane ----------------
#define GLL16(gptr, lptr) __builtin_amdgcn_global_load_lds( \
    (const __attribute__((address_space(1))) u32*)(gptr),   \
    (__attribute__((address_space(3))) u32*)(lptr), 16, 0, 0)

// ---------------- BMx128 bf16 GEMM (BK=64, swizzled LDS), C = A * Bt^T + bias ----
// EPI 0: scatter Q/K -> [B,H,C,hd], V -> transposed [B,H,hd,C].  EPI 1: f32 C + bias.
template<int EPI, int BM>
__global__ __launch_bounds__(256) void k_gemm(
    const u16* __restrict__ A, const u16* __restrict__ Bt,
    int M, int N, int K, const float* __restrict__ bias,
    u16* __restrict__ Cq, u16* __restrict__ Ck, u16* __restrict__ Cv,
    float* __restrict__ Cf)
{
  constexpr int WCW = (BM == 128) ? 64 : 32;   // per-wave col width
  constexpr int NF = WCW / 16;                 // n-frags per wave
  __shared__ __align__(16) u16 As[BM * 64];
  __shared__ __align__(16) u16 Bs[128 * 64];
  const int t = threadIdx.x;
  const int l = t & 63, w = t >> 6;
  const int wr = (BM == 128) ? (w >> 1) : 0;
  const int wc = (BM == 128) ? (w & 1) : w;
  const int lr = l & 15, lg = l >> 4;
  const int swk = lr & 7;
  const int m0 = blockIdx.y * BM, n0 = blockIdx.x * 128;
  f32x4 acc[4][NF] = {};

  for (int k0 = 0; k0 < K; k0 += 64) {
#pragma unroll
    for (int s = 0; s < BM / 32; ++s) {        // A: BM*8 16B-units
      const int u = s * 256 + t;
      const int row = u >> 3, slot = (u & 7) ^ (row & 7);
      GLL16(A + (size_t)(m0 + row) * K + k0 + (slot << 3), As + (u << 3));
    }
#pragma unroll
    for (int s = 0; s < 4; ++s) {              // B: 1024 16B-units
      const int u = s * 256 + t;
      const int row = u >> 3, slot = (u & 7) ^ (row & 7);
      GLL16(Bt + (size_t)(n0 + row) * K + k0 + (slot << 3), Bs + (u << 3));
    }
    __syncthreads();
    short8 af[2][4], bfr[2][NF];
#pragma unroll
    for (int s = 0; s < 2; ++s) {
#pragma unroll
      for (int m = 0; m < 4; ++m)
        af[s][m] = *reinterpret_cast<const short8*>(
            &As[((wr * 64 + m * 16 + lr) << 6) + (((s * 4 + lg) ^ swk) << 3)]);
#pragma unroll
      for (int n = 0; n < NF; ++n)
        bfr[s][n] = *reinterpret_cast<const short8*>(
            &Bs[((wc * WCW + n * 16 + lr) << 6) + (((s * 4 + lg) ^ swk) << 3)]);
    }
#pragma unroll
    for (int s = 0; s < 2; ++s)
#pragma unroll
      for (int m = 0; m < 4; ++m)
#pragma unroll
        for (int n = 0; n < NF; ++n)
          acc[m][n] = __builtin_amdgcn_mfma_f32_16x16x32_bf16(af[s][m], bfr[s][n], acc[m][n], 0, 0, 0);
    __syncthreads();
  }

#pragma unroll
  for (int m = 0; m < 4; ++m) {
    const int mg = m0 + wr * 64 + m * 16 + lg * 4;
    const int bq = mg >> 11, c0 = mg & 2047;
#pragma unroll
    for (int n = 0; n < NF; ++n) {
      const int ng = n0 + wc * WCW + n * 16 + lr;
      const float bia = bias[ng];
      if (EPI == 0) {
        const int reg = ng >> 10, d = ng & 1023, h = d >> 6, e = d & 63;
        if (reg == 2) {
          u16* vp = Cv + (((size_t)(bq * H_ + h) * HD_ + e) << 11) + c0;  // [B,H,hd,C]
#pragma unroll
          for (int j = 0; j < 4; ++j) vp[j] = f2b(acc[m][n][j] + bia);
        } else {
          u16* dst = (reg == 0) ? Cq : Ck;
#pragma unroll
          for (int j = 0; j < 4; ++j)
            dst[(((size_t)(bq * H_ + h) * C_ + c0 + j) << 6) + e] = f2b(acc[m][n][j] + bia);
        }
      } else {
#pragma unroll
        for (int j = 0; j < 4; ++j)
          Cf[(size_t)(mg + j) * N + ng] = acc[m][n][j] + bia;
      }
    }
  }
}

// stage one K tile [64 keys][64 hd] and one Vt tile [64 hd][64 keys] via DMA.
// LDS linear dest; source 16B-slot pre-XOR-swizzled (T21): slot ^= row&7.
static __device__ __forceinline__ void stage_kv(
    const u16* __restrict__ Kbh, const u16* __restrict__ Vbh,
    u16* Kd, u16* Vd, int kt, int t)
{
#pragma unroll
  for (int ch = 0; ch < 2; ++ch) {
    const int u = ch * 256 + t;
    const int row = u >> 3, slot = (u & 7) ^ (row & 7);
    GLL16(Kbh + (((size_t)(kt * 64 + row)) << 6) + (slot << 3), Kd + (u << 3));
    GLL16(Vbh + (((size_t)row) << 11) + kt * 64 + (slot << 3), Vd + (u << 3));
  }
}

// ---------------- causal flash attention (v8 revert: best measured, 56.7us) ------
// grid: 768 = 24 segs x 32 bh (longest-first; bid%8 == bh%8 -> XCD-local K/V).
// qt 0..7: one segment, direct normalized output. qt 8..15: two segments
// (tiles 0..15 / 16..ntiles); each writes NORMALIZED partial Ohat = O/l (bf16)
// + (m,l) f32; k_merge combines.
__global__ __launch_bounds__(256) void k_attn(
    const u16* __restrict__ Q, const u16* __restrict__ Kb, const u16* __restrict__ Vt,
    const float* __restrict__ mask, const u32* __restrict__ flags,
    u16* __restrict__ O, u16* __restrict__ Opart, float2* __restrict__ ml)
{
  __shared__ __align__(16) u16 Kl[2][64 * 64];
  __shared__ __align__(16) u16 Vl[2][64 * 64];
  __shared__ __align__(16) u16 Sc[4][2304];   // per-warp: P [32][64] (4KB) / Ol 32x144B
  const int bid = blockIdx.x;
  const int bh = bid & 31;                    // bid%8 == bh%8 -> XCD-local K/V
  const int sidx = 23 - (bid >> 5);           // longest segments dispatch first
  int qt, seg, nseg;
  if (sidx < 8) { qt = sidx; seg = 0; nseg = 1; }
  else          { const int u = sidx - 8; qt = 8 + (u >> 1); seg = u & 1; nseg = 2; }
  const int ntiles = 2 * qt + 2;
  const int kt0 = seg * 16;                   // even -> prologue buffer parity ok
  const int kt1 = seg ? ntiles : ((ntiles < 16) ? ntiles : 16);
  const int slot = ((bh << 3) + (qt - 8)) * 2 + seg;   // valid when nseg==2

  const int b = bh >> 4, h = bh & 15;
  const int t = threadIdx.x;
  const int l = t & 63, w = t >> 6;
  const int q = l & 31, hi = l >> 5;
  const int q7 = q & 7;

  const u16* Kbh = Kb + (size_t)bh * (C_ * HD_);
  const u16* Vbh = Vt + (size_t)bh * (HD_ * C_);
  char* Swb = reinterpret_cast<char*>(Sc[w]);

  const int q0w = qt * 128 + w * 32;
  const int qg = q0w + q;
  const int qmaxw = q0w + 31;

  // Q frags (B-operand: lane q=lane&31, k-slice=8*hi+i), pre-scaled by hd^-0.5
  short8 aq[4];
  {
    const u16* qp = Q + ((size_t)bh * C_ + qg) * HD_ + hi * 8;
#pragma unroll
    for (int kh = 0; kh < 4; ++kh) {
      short8 v = *reinterpret_cast<const short8*>(qp + kh * 16);
#pragma unroll
      for (int i = 0; i < 8; ++i) {
        const float f = b2f((u16)v[i]) * 0.125f;
        v[i] = (short)f2b(f);
      }
      aq[kh] = v;
    }
  }

  f32x16 oa0 = {}, oa1 = {};
  float mrun = -INFINITY, srun = 0.f;
  const float* mrow = mask + ((size_t)b * C_ + qg) * C_;
  const u32* fb = flags + (size_t)(b * 32 + (q0w >> 6)) * 32;

  stage_kv(Kbh, Vbh, Kl[0], Vl[0], kt0, t);

#pragma unroll 1
  for (int kt = kt0; kt < kt1; ++kt) {
    const int cur = kt & 1;
    __syncthreads();                        // drains own vmcnt + fence + barrier
    if (kt + 1 < kt1) stage_kv(Kbh, Vbh, Kl[cur ^ 1], Vl[cur ^ 1], kt + 1, t);
    if (kt * 64 > qmaxw) continue;          // warp fully past-causal for this tile

    const char* Kc = reinterpret_cast<const char*>(Kl[cur]);
    const char* Vc = reinterpret_cast<const char*>(Vl[cur]);

    // S^T = K Q^T : D[key][q]; p0 = keys kt*64+[0,32), p1 = +[32,64)
    f32x16 p0 = {}, p1 = {};
#pragma unroll
    for (int kh = 0; kh < 4; ++kh) {
      const int sl = ((2 * kh + hi) ^ q7) << 4;
      const short8 k0 = *reinterpret_cast<const short8*>(Kc + q * 128 + sl);
      const short8 k1 = *reinterpret_cast<const short8*>(Kc + (32 + q) * 128 + sl);
      p0 = __builtin_amdgcn_mfma_f32_32x32x16_bf16(k0, aq[kh], p0, 0, 0, 0);
      p1 = __builtin_amdgcn_mfma_f32_32x32x16_bf16(k1, aq[kh], p1, 0, 0, 0);
    }

    // additive mask (only when tile nonzero)
    if (fb[kt]) {
      const float* mp = mrow + kt * 64 + 4 * hi;
#pragma unroll
      for (int g = 0; g < 4; ++g) {
        const float4 m0 = *reinterpret_cast<const float4*>(mp + 8 * g);
        const float4 m1 = *reinterpret_cast<const float4*>(mp + 32 + 8 * g);
        p0[4*g+0] += m0.x; p0[4*g+1] += m0.y; p0[4*g+2] += m0.z; p0[4*g+3] += m0.w;
        p1[4*g+0] += m1.x; p1[4*g+1] += m1.y; p1[4*g+2] += m1.z; p1[4*g+3] += m1.w;
      }
    }
    // causal clamp (diagonal region only)
    if (kt * 64 + 63 > q0w) {
#pragma unroll
      for (int r = 0; r < 16; ++r) {
        const int kl = kt * 64 + (r & 3) + 8 * (r >> 2) + 4 * hi;
        if (kl > qg) p0[r] = -INFINITY;
        if (kl + 32 > qg) p1[r] = -INFINITY;
      }
    }

    // online softmax: in-lane over 32 scores + one cross-half shfl.
    float pm = -INFINITY;
#pragma unroll
    for (int r = 0; r < 16; ++r) pm = fmaxf(pm, fmaxf(p0[r], p1[r]));
    pm = fmaxf(pm, __shfl_xor(pm, 32));
    const float mn = fmaxf(fmaxf(mrun, pm), -1e30f);
    const float rs = __expf(mrun - mn);     // first iter: exp(-inf)=0
    float sum = 0.f;
#pragma unroll
    for (int r = 0; r < 16; ++r) {
      p0[r] = __expf(p0[r] - mn); sum += p0[r];
      p1[r] = __expf(p1[r] - mn); sum += p1[r];
    }
    sum += __shfl_xor(sum, 32);
    srun = srun * rs + sum;
    mrun = mn;
    oa0 *= rs; oa1 *= rs;

    // P -> per-warp LDS [32 q][64 keys], 16B-slot swizzled by q&7
#pragma unroll
    for (int g = 0; g < 4; ++g) {
#pragma unroll
      for (int m = 0; m < 2; ++m) {
        u32 w0, w1;
        asm("v_cvt_pk_bf16_f32 %0, %1, %2" : "=v"(w0) : "v"(p0[4*g+2*m]), "v"(p0[4*g+2*m+1]));
        asm("v_cvt_pk_bf16_f32 %0, %1, %2" : "=v"(w1) : "v"(p1[4*g+2*m]), "v"(p1[4*g+2*m+1]));
        *reinterpret_cast<u32*>(Swb + q * 128 + ((g ^ q7) << 4) + 8 * hi + 4 * m) = w0;
        *reinterpret_cast<u32*>(Swb + q * 128 + (((4 + g) ^ q7) << 4) + 8 * hi + 4 * m) = w1;
      }
    }
    asm volatile("" ::: "memory");          // order same-wave LDS write -> read

    // O^T += Vt x P : D[d][q]
#pragma unroll
    for (int ks = 0; ks < 4; ++ks) {
      const int sl = ((2 * ks + hi) ^ q7) << 4;
      const short8 bp = *reinterpret_cast<const short8*>(Swb + q * 128 + sl);
      const short8 v0 = *reinterpret_cast<const short8*>(Vc + q * 128 + sl);
      const short8 v1 = *reinterpret_cast<const short8*>(Vc + (32 + q) * 128 + sl);
      oa0 = __builtin_amdgcn_mfma_f32_32x32x16_bf16(v0, bp, oa0, 0, 0, 0);
      oa1 = __builtin_amdgcn_mfma_f32_32x32x16_bf16(v1, bp, oa1, 0, 0, 0);
    }
  }

  // epilogue: normalize (both paths!), transpose via per-warp LDS, vector store
  const float rinv = 1.f / srun;
#pragma unroll
  for (int g = 0; g < 4; ++g) {
    const int d0 = 8 * g + 4 * hi;
    const float a0 = oa0[4*g+0] * rinv, a1 = oa0[4*g+1] * rinv;
    const float a2 = oa0[4*g+2] * rinv, a3 = oa0[4*g+3] * rinv;
    const float b0 = oa1[4*g+0] * rinv, b1 = oa1[4*g+1] * rinv;
    const float b2 = oa1[4*g+2] * rinv, b3 = oa1[4*g+3] * rinv;
    u32 w0, w1, w2, w3;
    asm("v_cvt_pk_bf16_f32 %0, %1, %2" : "=v"(w0) : "v"(a0), "v"(a1));
    asm("v_cvt_pk_bf16_f32 %0, %1, %2" : "=v"(w1) : "v"(a2), "v"(a3));
    asm("v_cvt_pk_bf16_f32 %0, %1, %2" : "=v"(w2) : "v"(b0), "v"(b1));
    asm("v_cvt_pk_bf16_f32 %0, %1, %2" : "=v"(w3) : "v"(b2), "v"(b3));
    *reinterpret_cast<uint2*>(Swb + q * 144 + d0 * 2) = make_uint2(w0, w1);
    *reinterpret_cast<uint2*>(Swb + q * 144 + (d0 + 32) * 2) = make_uint2(w2, w3);
  }
  asm volatile("" ::: "memory");            // order same-wave LDS write -> read
  const int q2 = l >> 1, hf = l & 1;
  if (nseg == 1) {
    u16* orow = O + ((size_t)b * C_ + q0w + q2) * D_ + h * 64 + hf * 32;
#pragma unroll
    for (int i = 0; i < 4; ++i) {
      const short8 v = *reinterpret_cast<const short8*>(Swb + q2 * 144 + hf * 64 + i * 16);
      *reinterpret_cast<short8*>(orow + i * 8) = v;
    }
  } else {
    u16* prow = Opart + (((size_t)slot * 128 + w * 32 + q2) << 6) + hf * 32;
#pragma unroll
    for (int i = 0; i < 4; ++i) {
      const short8 v = *reinterpret_cast<const short8*>(Swb + q2 * 144 + hf * 64 + i * 16);
      *reinterpret_cast<short8*>(prow + i * 8) = v;
    }
    if (hi == 0) ml[(size_t)slot * 128 + w * 32 + q] = make_float2(mrun, srun);
  }
}

// ---------------- merge split-KV partials (nseg == 2) ----------------
// grid 256 = 8 qt (8..15) x 32 bh; 256 thr: thread -> (q = t>>1, dhalf = t&1)
// Partials are NORMALIZED: O = (a0*Ohat0 + a1*Ohat1)/(a0+a1), a_s = e^(m_s-M) l_s
__global__ __launch_bounds__(256) void k_merge(
    const u16* __restrict__ Opart, const float2* __restrict__ ml, u16* __restrict__ O)
{
  const int bid = blockIdx.x;
  const int bh = bid & 31;
  const int qt = 8 + (bid >> 5);
  const int slot0 = ((bh << 3) + (qt - 8)) * 2;
  const int b = bh >> 4, h = bh & 15;
  const int t = threadIdx.x;
  const int q = t >> 1, dh = t & 1;

  const float2 v0 = ml[(size_t)slot0 * 128 + q];
  const float2 v1 = ml[(size_t)(slot0 + 1) * 128 + q];
  const float M = fmaxf(v0.x, v1.x);
  const float a0 = __expf(v0.x - M) * v0.y;
  const float a1 = __expf(v1.x - M) * v1.y;
  const float rT = 1.f / (a0 + a1);
  const float r0 = a0 * rT, r1 = a1 * rT;

  const u16* p0 = Opart + (((size_t)slot0 * 128 + q) << 6) + dh * 32;
  const u16* p1 = Opart + (((size_t)(slot0 + 1) * 128 + q) << 6) + dh * 32;
  u16* orow = O + ((size_t)b * C_ + qt * 128 + q) * D_ + h * 64 + dh * 32;
#pragma unroll
  for (int i = 0; i < 4; ++i) {
    const short8 x0 = *reinterpret_cast<const short8*>(p0 + i * 8);
    const short8 x1 = *reinterpret_cast<const short8*>(p1 + i * 8);
    short8 y;
#pragma unroll
    for (int j = 0; j < 8; ++j)
      y[j] = (short)f2b(r0 * b2f((u16)x0[j]) + r1 * b2f((u16)x1[j]));
    *reinterpret_cast<short8*>(orow + i * 8) = y;
  }
}

extern "C" void kernel_launch(void* const* d_in, const int* in_sizes, int n_in,
                              void* d_out, int out_size, void* d_ws, size_t ws_size,
                              hipStream_t stream) {
  const float* hs   = (const float*)d_in[0];
  const float* mask = (const float*)d_in[1];
  const float* Wqkv = (const float*)d_in[2];
  const float* bqkv = (const float*)d_in[3];
  const float* Wo   = (const float*)d_in[4];
  const float* bo   = (const float*)d_in[5];
  float* out = (float*)d_out;
  char* ws = (char*)d_ws;

  // time-phased layout (peak 56 MB):
  u16*    hsb   = (u16*)(ws);                   // 8 MB, dead after gemm0
  u16*    Opart = (u16*)(ws);                   // 8 MB, attn phase (overlays hsb)
  u16*    Wqkvt = (u16*)(ws + (8  << 20));      // 6 MB
  float2* mlbuf = (float2*)(ws + (19 << 20));   // 512 KB [512 slots][128]
  u32*    flags = (u32*)(ws + (20 << 20) + (1 << 19)); // 8 KB @20.5MB
  u16*    Wot   = (u16*)(ws + (21 << 20));      // 2 MB
  u16*    Qb    = (u16*)(ws + (24 << 20));      // 8 MB [2,16,2048,64]
  u16*    Kb    = (u16*)(ws + (32 << 20));      // 8 MB [2,16,2048,64]
  u16*    Vtb   = (u16*)(ws + (40 << 20));      // 8 MB [2,16,64,2048]
  u16*    AOb   = (u16*)(ws + (48 << 20));      // 8 MB [4096][1024]

  k_prep<<<5120, 256, 0, stream>>>(hs, hsb, Wqkv, Wqkvt, Wo, Wot, mask, flags);
  k_gemm<0, 128><<<dim3(24, 32), 256, 0, stream>>>(hsb, Wqkvt, 4096, 3072, 1024, bqkv,
                                                   Qb, Kb, Vtb, nullptr);
  k_attn<<<768, 256, 0, stream>>>(Qb, Kb, Vtb, mask, flags, AOb, Opart, mlbuf);
  k_merge<<<256, 256, 0, stream>>>(Opart, mlbuf, AOb);
  k_gemm<1, 64><<<dim3(8, 64), 256, 0, stream>>>(AOb, Wot, 4096, 1024, 1024, bo,
                                                 nullptr, nullptr, nullptr, out);
}